// Round 25
// baseline (94.477 us; speedup 1.0000x reference)
//
#include <hip/hip_runtime.h>

typedef short short8 __attribute__((ext_vector_type(8)));
typedef float f32x4 __attribute__((ext_vector_type(4)));
typedef float f32x16 __attribute__((ext_vector_type(16)));
typedef unsigned short ushort_t;

__device__ inline ushort_t f2bf(float f) {
    union { float f; unsigned int u; } x{f};
    unsigned int r = (x.u + 0x7fffu + ((x.u >> 16) & 1u)) >> 16;
    return (ushort_t)r;
}
__device__ inline float bf2f(ushort_t u) {
    union { unsigned int u; float f; } x{(unsigned int)u << 16};
    return x.f;
}

__device__ inline void gload_lds16(const void* g, void* l) {
    __builtin_amdgcn_global_load_lds(
        (const __attribute__((address_space(1))) unsigned int*)g,
        (__attribute__((address_space(3))) unsigned int*)l, 16, 0, 0);
}

template <int CTRL>
__device__ inline float dppadd(float x) {
    union { float f; int i; } u, v;
    u.f = x;
    v.i = __builtin_amdgcn_update_dpp(0, u.i, CTRL, 0xf, 0xf, true);
    return x + v.f;
}
#define DPP_XOR1 0xB1
#define DPP_XOR2 0x4E
#define DPP_HMIR 0x141
#define DPP_MIR  0x140

// ---------- kernel 0: W [1024][128] f32 -> Wt [128][1024] bf16 (x3) ----------
__global__ __launch_bounds__(1024) void wt_prep(const float* __restrict__ Wq,
                                                const float* __restrict__ Wk,
                                                const float* __restrict__ Wv,
                                                ushort_t* __restrict__ Wt) {
    __shared__ float t[32][33];
    int bz = blockIdx.z;
    const float* W = bz == 0 ? Wq : (bz == 1 ? Wk : Wv);
    int h0 = blockIdx.x * 32, c0 = blockIdx.y * 32;
    int tx = threadIdx.x, ty = threadIdx.y;
    t[ty][tx] = W[(c0 + ty) * 128 + h0 + tx];
    __syncthreads();
    Wt[bz * 131072 + (h0 + ty) * 1024 + c0 + tx] = f2bf(t[tx][ty]);
}

// ---------- kernel 1: X [16384][1024] f32 @ Wt^T -> bf16 Q/K, V (transposed) ----------
// r7-measured BM=64 structure (timed ~33us = stream floor). FROZEN.
__global__ __launch_bounds__(256, 4) void proj_gemm(const float* __restrict__ q,
                                                    const float* __restrict__ k,
                                                    const float* __restrict__ v,
                                                    const ushort_t* __restrict__ Wt,
                                                    ushort_t* __restrict__ Qb,
                                                    ushort_t* __restrict__ Kb,
                                                    ushort_t* __restrict__ Vt) {
    __shared__ ushort_t lA[64][72];    // 9.2 KB
    __shared__ ushort_t lB[128][72];   // 18.4 KB
    int z = blockIdx.z;
    const float* X = z == 0 ? q : (z == 1 ? k : v);
    const ushort_t* Wz = Wt + z * 131072;
    int m0 = blockIdx.x * 64;
    int tid = threadIdx.x;
    int lane = tid & 63, wv = tid >> 6;
    int g = lane >> 4, li = lane & 15;

    f32x4 z4 = {0.f, 0.f, 0.f, 0.f};
    f32x4 acc[8];
#pragma unroll
    for (int n = 0; n < 8; ++n) acc[n] = z4;

    for (int ks = 0; ks < 16; ++ks) {
        int k0 = ks * 64;
        if (ks) __syncthreads();
#pragma unroll
        for (int it = 0; it < 4; ++it) {
            int idx = it * 256 + tid;
            int row = idx >> 4, c4 = idx & 15;
            const float4 val = *(const float4*)(X + (size_t)(m0 + row) * 1024 + k0 + c4 * 4);
            ushort4 bb;
            bb.x = f2bf(val.x); bb.y = f2bf(val.y); bb.z = f2bf(val.z); bb.w = f2bf(val.w);
            *(ushort4*)&lA[row][c4 * 4] = bb;
        }
#pragma unroll
        for (int it = 0; it < 4; ++it) {
            int idx = it * 256 + tid;
            int h = idx >> 3, k8 = idx & 7;
            *(int4*)&lB[h][k8 * 8] = *(const int4*)(Wz + h * 1024 + k0 + k8 * 8);
        }
        __syncthreads();
#pragma unroll
        for (int kk = 0; kk < 2; ++kk) {
            short8 a = *(const short8*)&lA[wv * 16 + li][kk * 32 + g * 8];
            short8 b[8];
#pragma unroll
            for (int n = 0; n < 8; ++n)
                b[n] = *(const short8*)&lB[n * 16 + li][kk * 32 + g * 8];
#pragma unroll
            for (int n = 0; n < 8; ++n)
                acc[n] = __builtin_amdgcn_mfma_f32_16x16x32_bf16(a, b[n], acc[n], 0, 0, 0);
        }
    }
    if (z < 2) {
        ushort_t* Out = z == 0 ? Qb : Kb;
        int rbase = m0 + wv * 16 + g * 4;
#pragma unroll
        for (int n = 0; n < 8; ++n)
#pragma unroll
            for (int r = 0; r < 4; ++r)
                Out[(size_t)(rbase + r) * 128 + n * 16 + li] = f2bf(acc[n][r]);
    } else {
        int tbase = m0 + wv * 16 + g * 4;
#pragma unroll
        for (int n = 0; n < 8; ++n)
#pragma unroll
            for (int r = 0; r < 4; ++r) {
                int t = tbase + r;
                int bb = t >> 11, tl = t & 2047;
                Vt[((size_t)bb * 128 + n * 16 + li) * 2048 + tl] = f2bf(acc[n][r]);
            }
    }
}

// ---------- kernel 2: flash attention pass 1, causal (j <= i+1), SPLIT-KV x2 ----------
// r20 structure re-expressed with 32x32x16 MFMA: 2 waves x 32 q-rows (same QBLK=64,
// same split-KV, same staging) -> each wave reads the full K/V LDS tiles, so halving
// the wave count HALVES redundant LDS read traffic (the quantified per-tile cost).
// C/D layout (m74/m101): col=lane&31, row=(reg&3)+8*(reg>>2)+4*(lane>>5).
// K swizzle upgraded to ^(row&15) (2-way reads); P rows padded to 76 (2-way).
__global__ __launch_bounds__(128) void attn_fwd(const ushort_t* __restrict__ Qb,
                                                const ushort_t* __restrict__ Kb,
                                                const ushort_t* __restrict__ Vt,
                                                ushort_t* __restrict__ oPb,
                                                float* __restrict__ lPf) {
    constexpr float SCL = 0.08838834764831845f * 1.4426950408889634f; // 1/sqrt(128)*log2(e)
    constexpr float MB  = 8.0f * 1.4426950408889634f;                 // fixed max (scaled)
    __shared__ ushort_t Kl[2][64][128];   // 32 KB, chunk c of row at slot c^(row&15)
    __shared__ ushort_t Vl[2][128][64];   // 32 KB, chunk c of row at slot c^(row&7)
    __shared__ ushort_t lP[2][32][76];    // 9.5 KB (152B rows -> 2-way reads)

    int t = threadIdx.x;                  // 0..127
    int lane = t & 63, wv = t >> 6;       // wv in {0,1}
    int l31 = lane & 31, h = lane >> 5;
    int b = blockIdx.x & 7;
    int idx = blockIdx.x >> 3;            // 0..63
    int qb = 31 - (idx >> 1);             // longest first
    int s  = idx & 1;                     // KV-half
    int r0 = qb * 64 + wv * 32;
    int NT = qb + 2; if (NT > 32) NT = 32;
    int h0 = (NT + 1) >> 1;
    int jb = s ? h0 : 0;
    int je = s ? NT : h0;
    const ushort_t* kb0 = Kb + (size_t)b * 2048 * 128;
    const ushort_t* vb0 = Vt + (size_t)b * 128 * 2048;
    ushort_t (*P)[76] = lP[wv];

    // Q fragments: lane holds Q[r0+l31][ks*16 + h*8 + 0..7], ks = 0..7
    short8 qf[8];
    const ushort_t* qrow = Qb + (size_t)(b * 2048 + r0 + l31) * 128 + h * 8;
#pragma unroll
    for (int ks = 0; ks < 8; ++ks) qf[ks] = *(const short8*)(qrow + ks * 16);

    f32x16 o[4];
#pragma unroll
    for (int n = 0; n < 4; ++n)
#pragma unroll
        for (int r = 0; r < 16; ++r) o[n][r] = 0.f;
    float lr[16];
#pragma unroll
    for (int r = 0; r < 16; ++r) lr[r] = 0.f;

    auto STAGE = [&](int jt, int buf) {
        int j0 = jt * 64;
        // K tile 16KB: 8 rounds x 8 rows x 256B. slot t&15, chunk c = slot^(row&15),
        // row&15 = (rr&1)*8 + (t>>4).
#pragma unroll
        for (int rr = 0; rr < 8; ++rr) {
            int row = rr * 8 + (t >> 4);
            int c = (t & 15) ^ ((rr & 1) * 8 + (t >> 4));
            gload_lds16(kb0 + (size_t)(j0 + row) * 128 + c * 8,
                        (char*)&Kl[buf][0][0] + rr * 2048 + t * 16);
        }
        // V tile 16KB: 8 rounds x 16 rows x 128B. slot t&7, chunk c = slot^(row&7).
#pragma unroll
        for (int rr = 0; rr < 8; ++rr) {
            int row = rr * 16 + (t >> 3);
            int c = (t & 7) ^ ((t >> 3) & 7);
            gload_lds16(vb0 + (size_t)row * 2048 + j0 + c * 8,
                        (char*)&Vl[buf][0][0] + rr * 2048 + t * 16);
        }
    };

    STAGE(jb, 0);
    asm volatile("s_waitcnt vmcnt(0)" ::: "memory");
    __builtin_amdgcn_s_barrier();

    for (int jt = jb; jt < je; ++jt) {
        int buf = (jt - jb) & 1;
        int j0 = jt * 64;
        if (jt + 1 < je) STAGE(jt + 1, buf ^ 1);
        const char* kb = (const char*)&Kl[buf][0][0];
        const char* vb = (const char*)&Vl[buf][0][0];

        // QK^T per 32-j half: S[q=r0+qrow(reg,h)][j=j0+jf*32+l31]
#pragma unroll
        for (int jf = 0; jf < 2; ++jf) {
            f32x16 sf;
#pragma unroll
            for (int r = 0; r < 16; ++r) sf[r] = 0.f;
            int row_t = jf * 32 + l31;
#pragma unroll
            for (int ks = 0; ks < 8; ++ks) {
                int slot = (ks * 2 + h) ^ (l31 & 15);
                short8 kfrag = *(const short8*)(kb + row_t * 256 + slot * 16);
                sf = __builtin_amdgcn_mfma_f32_32x32x16_bf16(qf[ks], kfrag, sf, 0, 0, 0);
            }
            if (j0 + 63 > r0 + 1) {
                int j = j0 + jf * 32 + l31;
#pragma unroll
                for (int r = 0; r < 16; ++r) {
                    int i = r0 + (r & 3) + 8 * (r >> 2) + 4 * h;
                    if (j > i + 1) sf[r] = -1e30f;
                }
            }
#pragma unroll
            for (int r = 0; r < 16; ++r) {
                float p = exp2f(sf[r] * SCL - MB);
                lr[r] += p;
                P[(r & 3) + 8 * (r >> 2) + 4 * h][jf * 32 + l31] = f2bf(p);
            }
        }
        // wave-internal RAW through LDS P (rule 18: drain + fence)
        asm volatile("s_waitcnt lgkmcnt(0)" ::: "memory");
        __builtin_amdgcn_sched_barrier(0);
        short8 pa[4];
#pragma unroll
        for (int js = 0; js < 4; ++js)
            pa[js] = *(const short8*)((const char*)&P[0][0] + l31 * 152 + js * 32 + h * 16);
        // PV: O[q][d=n*32+l31] += P[q][js*16+h*8+..] * V[same j][d]
#pragma unroll
        for (int n = 0; n < 4; ++n) {
            int d = n * 32 + l31;
#pragma unroll
            for (int js = 0; js < 4; ++js) {
                int slot = (js * 2 + h) ^ (l31 & 7);
                short8 vf = *(const short8*)(vb + d * 128 + slot * 16);
                o[n] = __builtin_amdgcn_mfma_f32_32x32x16_bf16(pa[js], vf, o[n], 0, 0, 0);
            }
        }
        asm volatile("s_waitcnt vmcnt(0)" ::: "memory");
        __builtin_amdgcn_s_barrier();
    }

    // row-sum reduce over j-lanes (bits 0-3 via DPP, bit 4 via shfl); keep h split
#pragma unroll
    for (int r = 0; r < 16; ++r) {
        lr[r] = dppadd<DPP_XOR1>(lr[r]);
        lr[r] = dppadd<DPP_XOR2>(lr[r]);
        lr[r] = dppadd<DPP_HMIR>(lr[r]);
        lr[r] = dppadd<DPP_MIR>(lr[r]);
        lr[r] += __shfl_xor(lr[r], 16);
    }
    if (l31 == 0) {
#pragma unroll
        for (int r = 0; r < 16; ++r)
            lPf[s * 16384 + b * 2048 + r0 + (r & 3) + 8 * (r >> 2) + 4 * h] = lr[r];
    }
#pragma unroll
    for (int n = 0; n < 4; ++n)
#pragma unroll
        for (int r = 0; r < 16; ++r) {
            int qq = r0 + (r & 3) + 8 * (r >> 2) + 4 * h;
            oPb[((size_t)s * 16384 + b * 2048 + qq) * 128 + n * 32 + l31] = f2bf(o[n][r]);
        }
}

// ---------- kernel 3: combine: out = (o0+o1)/(l0+l1) ----------
__global__ __launch_bounds__(256) void attn_combine(const ushort_t* __restrict__ oPb,
                                                    const float* __restrict__ lPf,
                                                    float* __restrict__ Out) {
    int gid = blockIdx.x * 256 + threadIdx.x;   // 256K threads x 8 elems
    int row = gid >> 4;
    int c8 = (gid & 15) * 8;
    float inv = 1.0f / (lPf[row] + lPf[16384 + row]);
    const ushort_t* p0 = oPb + (size_t)row * 128 + c8;
    const ushort_t* p1 = p0 + (size_t)16384 * 128;
    short8 a = *(const short8*)p0;
    short8 bb = *(const short8*)p1;
    float* op = Out + (size_t)row * 128 + c8;
    float4 r0v, r1v;
    float* rp0 = (float*)&r0v;
    float* rp1 = (float*)&r1v;
#pragma unroll
    for (int j = 0; j < 4; ++j)
        rp0[j] = (bf2f((ushort_t)a[j]) + bf2f((ushort_t)bb[j])) * inv;
#pragma unroll
    for (int j = 0; j < 4; ++j)
        rp1[j] = (bf2f((ushort_t)a[4 + j]) + bf2f((ushort_t)bb[4 + j])) * inv;
    *(float4*)op = r0v;
    *(float4*)(op + 4) = r1v;
}

extern "C" void kernel_launch(void* const* d_in, const int* in_sizes, int n_in,
                              void* d_out, int out_size, void* d_ws, size_t ws_size,
                              hipStream_t stream) {
    const float* q  = (const float*)d_in[0];
    const float* k  = (const float*)d_in[1];
    const float* v  = (const float*)d_in[2];
    const float* Wq = (const float*)d_in[3];
    const float* Wk = (const float*)d_in[4];
    const float* Wv = (const float*)d_in[5];
    float* Out = (float*)d_out;

    ushort_t* Qb  = (ushort_t*)d_ws;         // [16384][128] bf16       4 MB
    ushort_t* Kb  = Qb + 2097152;            // [16384][128] bf16       4 MB
    ushort_t* Vt  = Kb + 2097152;            // [8][128][2048] bf16     4 MB
    ushort_t* Wt  = Vt + 2097152;            // [3][128][1024] bf16   0.75 MB
    ushort_t* oPb = Wt + 393216;             // [2][16384][128] bf16    8 MB
    float*    lPf = (float*)(oPb + 4194304); // [2][16384] f32       0.13 MB   total ~20.9 MB

    wt_prep<<<dim3(4, 32, 3), dim3(32, 32), 0, stream>>>(Wq, Wk, Wv, Wt);
    proj_gemm<<<dim3(256, 1, 3), 256, 0, stream>>>(q, k, v, Wt, Qb, Kb, Vt);
    attn_fwd<<<dim3(512), 128, 0, stream>>>(Qb, Kb, Vt, oPb, lPf);
    attn_combine<<<dim3(1024), 256, 0, stream>>>(oPb, lPf, Out);
}

// Round 26
// 79.128 us; speedup vs baseline: 1.1940x; 1.1940x over previous
//
#include <hip/hip_runtime.h>

typedef short short8 __attribute__((ext_vector_type(8)));
typedef float f32x4 __attribute__((ext_vector_type(4)));
typedef unsigned short ushort_t;

__device__ inline ushort_t f2bf(float f) {
    union { float f; unsigned int u; } x{f};
    unsigned int r = (x.u + 0x7fffu + ((x.u >> 16) & 1u)) >> 16;
    return (ushort_t)r;
}
__device__ inline float bf2f(ushort_t u) {
    union { unsigned int u; float f; } x{(unsigned int)u << 16};
    return x.f;
}

__device__ inline void gload_lds16(const void* g, void* l) {
    __builtin_amdgcn_global_load_lds(
        (const __attribute__((address_space(1))) unsigned int*)g,
        (__attribute__((address_space(3))) unsigned int*)l, 16, 0, 0);
}

template <int CTRL>
__device__ inline float dppadd(float x) {
    union { float f; int i; } u, v;
    u.f = x;
    v.i = __builtin_amdgcn_update_dpp(0, u.i, CTRL, 0xf, 0xf, true);
    return x + v.f;
}
#define DPP_XOR1 0xB1
#define DPP_XOR2 0x4E
#define DPP_HMIR 0x141
#define DPP_MIR  0x140

// ---------- kernel 0: W [1024][128] f32 -> Wt [128][1024] bf16 (x3) ----------
__global__ __launch_bounds__(1024) void wt_prep(const float* __restrict__ Wq,
                                                const float* __restrict__ Wk,
                                                const float* __restrict__ Wv,
                                                ushort_t* __restrict__ Wt) {
    __shared__ float t[32][33];
    int bz = blockIdx.z;
    const float* W = bz == 0 ? Wq : (bz == 1 ? Wk : Wv);
    int h0 = blockIdx.x * 32, c0 = blockIdx.y * 32;
    int tx = threadIdx.x, ty = threadIdx.y;
    t[ty][tx] = W[(c0 + ty) * 128 + h0 + tx];
    __syncthreads();
    Wt[bz * 131072 + (h0 + ty) * 1024 + c0 + tx] = f2bf(t[tx][ty]);
}

// ---------- kernel 1: X [16384][1024] f32 @ Wt^T -> bf16 Q/K, V (transposed) ----------
// r7-measured BM=64 structure (timed ~33us = 201MB fp32 @ ~6.1 TB/s stream floor).
// FROZEN (r16 pipeline and r23 BM=32 both regressed).
__global__ __launch_bounds__(256, 4) void proj_gemm(const float* __restrict__ q,
                                                    const float* __restrict__ k,
                                                    const float* __restrict__ v,
                                                    const ushort_t* __restrict__ Wt,
                                                    ushort_t* __restrict__ Qb,
                                                    ushort_t* __restrict__ Kb,
                                                    ushort_t* __restrict__ Vt) {
    __shared__ ushort_t lA[64][72];    // 9.2 KB
    __shared__ ushort_t lB[128][72];   // 18.4 KB
    int z = blockIdx.z;
    const float* X = z == 0 ? q : (z == 1 ? k : v);
    const ushort_t* Wz = Wt + z * 131072;
    int m0 = blockIdx.x * 64;
    int tid = threadIdx.x;
    int lane = tid & 63, wv = tid >> 6;
    int g = lane >> 4, li = lane & 15;

    f32x4 z4 = {0.f, 0.f, 0.f, 0.f};
    f32x4 acc[8];
#pragma unroll
    for (int n = 0; n < 8; ++n) acc[n] = z4;

    for (int ks = 0; ks < 16; ++ks) {
        int k0 = ks * 64;
        if (ks) __syncthreads();
#pragma unroll
        for (int it = 0; it < 4; ++it) {
            int idx = it * 256 + tid;
            int row = idx >> 4, c4 = idx & 15;
            const float4 val = *(const float4*)(X + (size_t)(m0 + row) * 1024 + k0 + c4 * 4);
            ushort4 bb;
            bb.x = f2bf(val.x); bb.y = f2bf(val.y); bb.z = f2bf(val.z); bb.w = f2bf(val.w);
            *(ushort4*)&lA[row][c4 * 4] = bb;
        }
#pragma unroll
        for (int it = 0; it < 4; ++it) {
            int idx = it * 256 + tid;
            int h = idx >> 3, k8 = idx & 7;
            *(int4*)&lB[h][k8 * 8] = *(const int4*)(Wz + h * 1024 + k0 + k8 * 8);
        }
        __syncthreads();
#pragma unroll
        for (int kk = 0; kk < 2; ++kk) {
            short8 a = *(const short8*)&lA[wv * 16 + li][kk * 32 + g * 8];
            short8 b[8];
#pragma unroll
            for (int n = 0; n < 8; ++n)
                b[n] = *(const short8*)&lB[n * 16 + li][kk * 32 + g * 8];
#pragma unroll
            for (int n = 0; n < 8; ++n)
                acc[n] = __builtin_amdgcn_mfma_f32_16x16x32_bf16(a, b[n], acc[n], 0, 0, 0);
        }
    }
    if (z < 2) {
        ushort_t* Out = z == 0 ? Qb : Kb;
        int rbase = m0 + wv * 16 + g * 4;
#pragma unroll
        for (int n = 0; n < 8; ++n)
#pragma unroll
            for (int r = 0; r < 4; ++r)
                Out[(size_t)(rbase + r) * 128 + n * 16 + li] = f2bf(acc[n][r]);
    } else {
        int tbase = m0 + wv * 16 + g * 4;
#pragma unroll
        for (int n = 0; n < 8; ++n)
#pragma unroll
            for (int r = 0; r < 4; ++r) {
                int t = tbase + r;
                int bb = t >> 11, tl = t & 2047;
                Vt[((size_t)bb * 128 + n * 16 + li) * 2048 + tl] = f2bf(acc[n][r]);
            }
    }
}

// ---------- kernel 2: flash attention pass 1, causal (j <= i+1), SPLIT-KV x2 ----------
// r20-proven structure (best measured: 79.3/79.5us total, reproduced twice).
// 16x16x32 MFMA, QBLK=64, 4 waves, double-buffered gload_lds K/V + rule-21 XOR
// swizzle, fixed-max softmax, split-KV x2 plain-sum partials. FROZEN — r25's
// 32x32 variant (2 waves) regressed: wave-count concurrency dominates LDS traffic.
__global__ __launch_bounds__(256) void attn_fwd(const ushort_t* __restrict__ Qb,
                                                const ushort_t* __restrict__ Kb,
                                                const ushort_t* __restrict__ Vt,
                                                ushort_t* __restrict__ oPb,
                                                float* __restrict__ lPf) {
    constexpr float SCL = 0.08838834764831845f * 1.4426950408889634f; // 1/sqrt(128)*log2(e)
    constexpr float MB  = 8.0f * 1.4426950408889634f;                 // fixed max (scaled)
    __shared__ ushort_t Kl[2][64][128];   // 32 KB
    __shared__ ushort_t Vl[2][128][64];   // 32 KB
    __shared__ ushort_t lP[4][16][72];    // 9.2 KB   (total 73.2 KB -> 2 blocks/CU)

    int t = threadIdx.x;
    int lane = t & 63, wv = t >> 6;
    int g = lane >> 4, li = lane & 15;
    int b = blockIdx.x & 7;
    int idx = blockIdx.x >> 3;            // 0..63
    int qb = 31 - (idx >> 1);             // longest first
    int s  = idx & 1;                     // KV-half
    int r0 = qb * 64 + wv * 16;
    int NT = qb + 2; if (NT > 32) NT = 32;
    int h0 = (NT + 1) >> 1;
    int jb = s ? h0 : 0;
    int je = s ? NT : h0;
    const ushort_t* kb0 = Kb + (size_t)b * 2048 * 128;
    const ushort_t* vb0 = Vt + (size_t)b * 128 * 2048;
    ushort_t (*P)[72] = lP[wv];

    short8 qf[4];
    const ushort_t* qrow = Qb + (size_t)(b * 2048 + r0 + li) * 128 + g * 8;
#pragma unroll
    for (int kf = 0; kf < 4; ++kf) qf[kf] = *(const short8*)(qrow + kf * 32);

    f32x4 z4 = {0.f, 0.f, 0.f, 0.f};
    f32x4 o[8];
#pragma unroll
    for (int n = 0; n < 8; ++n) o[n] = z4;
    float lr[4] = {0.f, 0.f, 0.f, 0.f};

    auto STAGE = [&](int jt, int buf) {
        int j0 = jt * 64;
#pragma unroll
        for (int r = 0; r < 4; ++r) {
            int row = r * 16 + (t >> 4);
            int c = (t & 15) ^ ((t >> 4) & 7);
            gload_lds16(kb0 + (size_t)(j0 + row) * 128 + c * 8,
                        (char*)&Kl[buf][0][0] + r * 4096 + t * 16);
        }
#pragma unroll
        for (int r = 0; r < 4; ++r) {
            int row = r * 32 + (t >> 3);
            int c = (t & 7) ^ ((t >> 3) & 7);
            gload_lds16(vb0 + (size_t)row * 2048 + j0 + c * 8,
                        (char*)&Vl[buf][0][0] + r * 4096 + t * 16);
        }
    };

    STAGE(jb, 0);
    asm volatile("s_waitcnt vmcnt(0)" ::: "memory");
    __builtin_amdgcn_s_barrier();

    for (int jt = jb; jt < je; ++jt) {
        int buf = (jt - jb) & 1;
        int j0 = jt * 64;
        if (jt + 1 < je) STAGE(jt + 1, buf ^ 1);
        const char* kb = (const char*)&Kl[buf][0][0];
        const char* vb = (const char*)&Vl[buf][0][0];

        f32x4 sA[4];
#pragma unroll
        for (int jf = 0; jf < 4; ++jf) sA[jf] = z4;
#pragma unroll
        for (int jf = 0; jf < 4; ++jf)
#pragma unroll
            for (int kf = 0; kf < 4; ++kf) {
                short8 kfrag = *(const short8*)(kb + (jf * 16 + li) * 256 +
                                                (((kf * 4 + g) ^ (li & 7)) * 16));
                sA[jf] = __builtin_amdgcn_mfma_f32_16x16x32_bf16(qf[kf], kfrag, sA[jf], 0, 0, 0);
            }
        if (j0 + 63 > r0 + 1) {
#pragma unroll
            for (int jf = 0; jf < 4; ++jf)
#pragma unroll
                for (int r = 0; r < 4; ++r) {
                    int j = j0 + jf * 16 + li;
                    int i = r0 + g * 4 + r;
                    if (j > i + 1) sA[jf][r] = -1e30f;
                }
        }
#pragma unroll
        for (int jf = 0; jf < 4; ++jf)
#pragma unroll
            for (int r = 0; r < 4; ++r) {
                float p = exp2f(sA[jf][r] * SCL - MB);
                lr[r] += p;
                P[g * 4 + r][jf * 16 + li] = f2bf(p);
            }
        // wave-internal RAW through LDS P (rule 18: drain + fence)
        asm volatile("s_waitcnt lgkmcnt(0)" ::: "memory");
        __builtin_amdgcn_sched_barrier(0);
        short8 pa0 = *(const short8*)&P[li][g * 8];
        short8 pa1 = *(const short8*)&P[li][32 + g * 8];
#pragma unroll
        for (int n = 0; n < 8; ++n) {
            short8 vf = *(const short8*)(vb + (n * 16 + li) * 128 +
                                         ((g ^ (li & 7)) * 16));
            o[n] = __builtin_amdgcn_mfma_f32_16x16x32_bf16(pa0, vf, o[n], 0, 0, 0);
        }
#pragma unroll
        for (int n = 0; n < 8; ++n) {
            short8 vf = *(const short8*)(vb + (n * 16 + li) * 128 +
                                         (((4 + g) ^ (li & 7)) * 16));
            o[n] = __builtin_amdgcn_mfma_f32_16x16x32_bf16(pa1, vf, o[n], 0, 0, 0);
        }
        asm volatile("s_waitcnt vmcnt(0)" ::: "memory");
        __builtin_amdgcn_s_barrier();
    }

#pragma unroll
    for (int r = 0; r < 4; ++r) {
        lr[r] = dppadd<DPP_XOR1>(lr[r]);
        lr[r] = dppadd<DPP_XOR2>(lr[r]);
        lr[r] = dppadd<DPP_HMIR>(lr[r]);
        lr[r] = dppadd<DPP_MIR>(lr[r]);
    }
    // partial epilogue: bf16 o-partials + f32 l-partials (no divide)
    if (li == 0) {
#pragma unroll
        for (int r = 0; r < 4; ++r)
            lPf[s * 16384 + b * 2048 + r0 + g * 4 + r] = lr[r];
    }
#pragma unroll
    for (int r = 0; r < 4; ++r) {
        size_t base = ((size_t)s * 16384 + b * 2048 + r0 + g * 4 + r) * 128 + li;
#pragma unroll
        for (int n = 0; n < 8; ++n)
            oPb[base + n * 16] = f2bf(o[n][r]);
    }
}

// ---------- kernel 3: combine: out = (o0+o1)/(l0+l1) ----------
__global__ __launch_bounds__(256) void attn_combine(const ushort_t* __restrict__ oPb,
                                                    const float* __restrict__ lPf,
                                                    float* __restrict__ Out) {
    int gid = blockIdx.x * 256 + threadIdx.x;   // 256K threads x 8 elems
    int row = gid >> 4;
    int c8 = (gid & 15) * 8;
    float inv = 1.0f / (lPf[row] + lPf[16384 + row]);
    const ushort_t* p0 = oPb + (size_t)row * 128 + c8;
    const ushort_t* p1 = p0 + (size_t)16384 * 128;
    short8 a = *(const short8*)p0;
    short8 bb = *(const short8*)p1;
    float* op = Out + (size_t)row * 128 + c8;
    float4 r0v, r1v;
    float* rp0 = (float*)&r0v;
    float* rp1 = (float*)&r1v;
#pragma unroll
    for (int j = 0; j < 4; ++j)
        rp0[j] = (bf2f((ushort_t)a[j]) + bf2f((ushort_t)bb[j])) * inv;
#pragma unroll
    for (int j = 0; j < 4; ++j)
        rp1[j] = (bf2f((ushort_t)a[4 + j]) + bf2f((ushort_t)bb[4 + j])) * inv;
    *(float4*)op = r0v;
    *(float4*)(op + 4) = r1v;
}

extern "C" void kernel_launch(void* const* d_in, const int* in_sizes, int n_in,
                              void* d_out, int out_size, void* d_ws, size_t ws_size,
                              hipStream_t stream) {
    const float* q  = (const float*)d_in[0];
    const float* k  = (const float*)d_in[1];
    const float* v  = (const float*)d_in[2];
    const float* Wq = (const float*)d_in[3];
    const float* Wk = (const float*)d_in[4];
    const float* Wv = (const float*)d_in[5];
    float* Out = (float*)d_out;

    ushort_t* Qb  = (ushort_t*)d_ws;         // [16384][128] bf16       4 MB
    ushort_t* Kb  = Qb + 2097152;            // [16384][128] bf16       4 MB
    ushort_t* Vt  = Kb + 2097152;            // [8][128][2048] bf16     4 MB
    ushort_t* Wt  = Vt + 2097152;            // [3][128][1024] bf16   0.75 MB
    ushort_t* oPb = Wt + 393216;             // [2][16384][128] bf16    8 MB
    float*    lPf = (float*)(oPb + 4194304); // [2][16384] f32       0.13 MB   total ~20.9 MB

    wt_prep<<<dim3(4, 32, 3), dim3(32, 32), 0, stream>>>(Wq, Wk, Wv, Wt);
    proj_gemm<<<dim3(256, 1, 3), 256, 0, stream>>>(q, k, v, Wt, Qb, Kb, Vt);
    attn_fwd<<<dim3(512), 256, 0, stream>>>(Qb, Kb, Vt, oPb, lPf);
    attn_combine<<<dim3(1024), 256, 0, stream>>>(oPb, lPf, Out);
}